// Round 1
// baseline (14469.519 us; speedup 1.0000x reference)
//
#include <hip/hip_runtime.h>
#include <math.h>

typedef __bf16 bf16x8 __attribute__((ext_vector_type(8)));
typedef float f32x4 __attribute__((ext_vector_type(4)));

namespace {

constexpr int kB = 16;
constexpr int kT = 1024;
constexpr int kD = 1024;
constexpr int kN = 8;
constexpr float kScale = 0.03125f;  // 1/sqrt(1024)

constexpr unsigned long long kSent = ~0ull;      // 8B poison
constexpr unsigned kSentW = 0xFFFFFFFFu;         // 4B poison word (NaN)
constexpr int kHS = 3 * kB * kD;                 // shorts per h-split parity buf
constexpr int kRW = 2 * kB * kD;                 // floats per rw parity buf

__device__ inline unsigned short f2bf(float f) {  // RNE f32->bf16 bits
  unsigned u = __float_as_uint(f);
  u += 0x7FFFu + ((u >> 16) & 1u);
  return (unsigned short)(u >> 16);
}
__device__ inline float bf2f(unsigned short b) {
  return __uint_as_float(((unsigned)b) << 16);
}

// Fence-free cross-block transfer: relaxed agent-scope atomics compile to
// sc0|sc1 (L1+L2-bypass) accesses served by the device-coherent point.
__device__ inline void atst8(void* p, unsigned long long v) {
  __hip_atomic_store((unsigned long long*)p, v, __ATOMIC_RELAXED,
                     __HIP_MEMORY_SCOPE_AGENT);
}
__device__ inline unsigned long long atld8(const void* p) {
  return __hip_atomic_load((unsigned long long*)p, __ATOMIC_RELAXED,
                           __HIP_MEMORY_SCOPE_AGENT);
}
__device__ inline void atstf(float* p, float v) {
  __hip_atomic_store(p, v, __ATOMIC_RELAXED, __HIP_MEMORY_SCOPE_AGENT);
}
__device__ inline void atstu(unsigned* p, unsigned v) {
  __hip_atomic_store(p, v, __ATOMIC_RELAXED, __HIP_MEMORY_SCOPE_AGENT);
}
__device__ inline unsigned atldu(const unsigned* p) {
  return __hip_atomic_load((unsigned*)p, __ATOMIC_RELAXED,
                           __HIP_MEMORY_SCOPE_AGENT);
}

union U16 { unsigned long long ll[2]; unsigned wrd[4]; bf16x8 bv; float4 f4; };

// ---------------------------------------------------------------------------
// x_proj GEMM (round-1 proven): C[m,n] = sum_k X[m,k]*Wx[n,k]
__global__ __launch_bounds__(256)
void xproj_kernel(const float* __restrict__ X, const float* __restrict__ Wx,
                  float* __restrict__ C) {
  __shared__ float Xs[16][132];
  __shared__ float Ws[16][132];
  const int tid = threadIdx.x;
  const int n0 = blockIdx.x * 128;
  const int m0 = blockIdx.y * 128;
  const int tx = tid & 15;
  const int ty = tid >> 4;
  const int lr = tid >> 2;
  const int lc = (tid & 3) * 4;

  float acc[8][8];
#pragma unroll
  for (int i = 0; i < 8; ++i)
#pragma unroll
    for (int j = 0; j < 8; ++j) acc[i][j] = 0.f;

  for (int k0 = 0; k0 < kD; k0 += 16) {
    const float4 xa = *(const float4*)&X[(size_t)(m0 + lr) * kD + k0 + lc];
    const float4 xb = *(const float4*)&X[(size_t)(m0 + lr + 64) * kD + k0 + lc];
    const float4 wa = *(const float4*)&Wx[(size_t)(n0 + lr) * kD + k0 + lc];
    const float4 wb = *(const float4*)&Wx[(size_t)(n0 + lr + 64) * kD + k0 + lc];
    __syncthreads();
    Xs[lc + 0][lr] = xa.x; Xs[lc + 1][lr] = xa.y; Xs[lc + 2][lr] = xa.z; Xs[lc + 3][lr] = xa.w;
    Xs[lc + 0][lr + 64] = xb.x; Xs[lc + 1][lr + 64] = xb.y; Xs[lc + 2][lr + 64] = xb.z; Xs[lc + 3][lr + 64] = xb.w;
    Ws[lc + 0][lr] = wa.x; Ws[lc + 1][lr] = wa.y; Ws[lc + 2][lr] = wa.z; Ws[lc + 3][lr] = wa.w;
    Ws[lc + 0][lr + 64] = wb.x; Ws[lc + 1][lr + 64] = wb.y; Ws[lc + 2][lr + 64] = wb.z; Ws[lc + 3][lr + 64] = wb.w;
    __syncthreads();
#pragma unroll
    for (int k = 0; k < 16; ++k) {
      float a[8], b[8];
      *(float4*)&a[0] = *(const float4*)&Xs[k][ty * 8];
      *(float4*)&a[4] = *(const float4*)&Xs[k][ty * 8 + 4];
      *(float4*)&b[0] = *(const float4*)&Ws[k][tx * 8];
      *(float4*)&b[4] = *(const float4*)&Ws[k][tx * 8 + 4];
#pragma unroll
      for (int i = 0; i < 8; ++i)
#pragma unroll
        for (int j = 0; j < 8; ++j) acc[i][j] += a[i] * b[j];
    }
  }
#pragma unroll
  for (int i = 0; i < 8; ++i) {
    float4 v0 = make_float4(acc[i][0], acc[i][1], acc[i][2], acc[i][3]);
    float4 v1 = make_float4(acc[i][4], acc[i][5], acc[i][6], acc[i][7]);
    float* p = &C[(size_t)(m0 + ty * 8 + i) * kD + n0 + tx * 8];
    *(float4*)p = v0;
    *(float4*)(p + 4) = v1;
  }
}

// ---------------------------------------------------------------------------
__device__ inline void store_split(unsigned short* hs, int b, int d4, float4 h) {
  union { unsigned short u[4]; unsigned long long ll; } c2, c1, c0;
  float hv[4] = {h.x, h.y, h.z, h.w};
#pragma unroll
  for (int e = 0; e < 4; ++e) {
    unsigned short x = f2bf(hv[e]);
    float r = hv[e] - bf2f(x);
    unsigned short y = f2bf(r);
    float r2 = r - bf2f(y);
    unsigned short z = f2bf(r2);
    c2.u[e] = x; c1.u[e] = y; c0.u[e] = z;
  }
  atst8(&hs[0 * 16384 + b * kD + d4], c2.ll);
  atst8(&hs[1 * 16384 + b * kD + d4], c1.ll);
  atst8(&hs[2 * 16384 + b * kD + d4], c0.ll);
}

// ---------------------------------------------------------------------------
// Persistent scan, 64 blocks x 256 threads (all resident; deadlock-safe).
//
// Sync protocol (this round's change; numerics identical to previous round):
//  * h broadcast: parity-double-buffered hsplit[2] + per-(batch,wave)
//    MONOTONIC markers hmark[w][b]. Producer wave w of tape block b writes
//    exactly the chunks consumer-wave w reads, so each wave drains its own
//    stores (s_waitcnt vmcnt(0)) and lane 0 bumps one 4B tag. No block-wide
//    barrier, no flag array, no poison needed (tags strictly increase).
//  * rh/wv gather: parity-double-buffered rw[2] with DATA-AS-FLAG. Buffers
//    are poisoned to 0xFFFFFFFF (NaN; unreachable by finite arithmetic).
//    Producers just fire 4B stores -- no drain, no flag. The consumer's
//    first load IS the poll (validated per 32-bit word, since the two
//    halves of an 8B chunk come from different producer threads). The
//    consumer re-poisons the 4 chunks it read; the poison is drained by the
//    next publish's pre-marker vmcnt(0), which orders it before the h-tag
//    that gates the producers' next write of this parity (no ABA).
__global__ __launch_bounds__(256, 1)
void scan_kernel(const float* __restrict__ Wh, const float* __restrict__ Ww,
                 const float* __restrict__ bh,
                 float* __restrict__ hall,              // [B,T,D] xp -> h
                 unsigned short* __restrict__ hsplit,   // [2][3][16][1024] bf16
                 float* __restrict__ rw,                // [2][2][16][1024] f32
                 unsigned* __restrict__ hmark,          // [4][16] tags
                 float* __restrict__ out_tape,          // [B,N,D]
                 float* __restrict__ out_h) {           // [B,D]
  const int g = blockIdx.x;
  const int tid = threadIdx.x;
  const int w = tid >> 6;    // wave 0..3 (split-K: k range [256w, 256w+256))
  const int ln = tid & 63;
  const int bat = ln & 15;   // A-row (batch) / B-col selector
  const int q = ln >> 4;     // k-chunk selector
  const bool tapeb = (g < kB);
  const int col0 = (g & 31) * 32;
  const int matw = g >> 5;

  __shared__ float tp[kN][kD];        // 32 KiB (tape blocks)
  __shared__ f32x4 Cred[4][2][64];    // 8 KiB cross-wave C partials
  __shared__ float red2[4][16];

  // ---- weight prologue (plain loads; weights immutable) ----
  bf16x8 wf[3][2][8];
  {
    const float* Wsrc = matw ? Ww : Wh;
#pragma unroll
    for (int ct = 0; ct < 2; ++ct)
#pragma unroll
      for (int j = 0; j < 8; ++j) {
        const float* src = &Wsrc[(size_t)(col0 + ct * 16 + bat) * kD + (w * 8 + j) * 32 + q * 8];
        float v[8];
        *(float4*)&v[0] = *(const float4*)src;
        *(float4*)&v[4] = *(const float4*)(src + 4);
        union { unsigned short u[8]; bf16x8 b; } e2, e1, e0;
#pragma unroll
        for (int e = 0; e < 8; ++e) {
          unsigned short a = f2bf(v[e]);
          float r = v[e] - bf2f(a);
          unsigned short b2 = f2bf(r);
          float r2 = r - bf2f(b2);
          unsigned short c = f2bf(r2);
          e2.u[e] = a; e1.u[e] = b2; e0.u[e] = c;
        }
        wf[0][ct][j] = e2.b;
        wf[1][ct][j] = e1.b;
        wf[2][ct][j] = e0.b;
      }
  }

  // ---- tape-block bootstrap: tape=0, h(1)=tanh(xp0), publish parity 0 ----
  float4 hprev = make_float4(0.f, 0.f, 0.f, 0.f);
  float4 bh4 = make_float4(0.f, 0.f, 0.f, 0.f);
  const int d4 = tid * 4;
  if (tapeb) {
    const size_t x0 = (size_t)g * kT * kD + d4;
    float4 xp0 = *(const float4*)&hall[x0];
    hprev.x = tanhf(xp0.x); hprev.y = tanhf(xp0.y);
    hprev.z = tanhf(xp0.z); hprev.w = tanhf(xp0.w);
    *(float4*)&hall[x0] = hprev;
    store_split(hsplit, g, d4, hprev);           // parity 0 = h(1)
    asm volatile("s_waitcnt vmcnt(0)" ::: "memory");  // wave-local drain
    if (ln == 0) atstu(&hmark[w * 16 + g], 1u);  // tag 1: h(1) ready
    bh4 = *(const float4*)&bh[d4];
    float4 z = make_float4(0.f, 0.f, 0.f, 0.f);
#pragma unroll
    for (int i = 0; i < 8; ++i) ((float4*)&tp[0][0])[i * 256 + tid] = z;
    __syncthreads();
  }

  for (int t = 0; t < kT; ++t) {
    const int p = t & 1;
    const unsigned short* hb = hsplit + p * kHS;

    // xp prefetch at the very top: HBM latency hides under the GEMV phase
    float4 xp4 = make_float4(0.f, 0.f, 0.f, 0.f);
    if (tapeb && t < kT - 1)
      xp4 = *(const float4*)&hall[((size_t)g * kT + (t + 1)) * kD + d4];

    // ---- phase 1: spin on h markers, then blast-load A fragments ----
    {
      const unsigned need = (unsigned)(t + 1);
      const unsigned* mk = &hmark[w * 16 + bat];
      while (atldu(mk) < need) __builtin_amdgcn_s_sleep(1);
    }
    bf16x8 af[3][8];
#pragma unroll
    for (int j = 0; j < 8; ++j) {
      const unsigned short* p0 = &hb[bat * kD + w * 256 + j * 32 + q * 8];
#pragma unroll
      for (int part = 0; part < 3; ++part) {
        U16 u;
        u.ll[0] = atld8(p0 + part * 16384);
        u.ll[1] = atld8(p0 + part * 16384 + 4);
        af[part][j] = u.bv;
      }
    }

    // ---- 6-product triple-split MFMA ----
    f32x4 zf = {0.f, 0.f, 0.f, 0.f};
    f32x4 acc[2][2] = {{zf, zf}, {zf, zf}};
#pragma unroll
    for (int j = 0; j < 8; ++j) {
      const int s = j & 1;
#pragma unroll
      for (int ct = 0; ct < 2; ++ct) {
        f32x4 a = acc[ct][s];
        a = __builtin_amdgcn_mfma_f32_16x16x32_bf16(af[0][j], wf[0][ct][j], a, 0, 0, 0);
        a = __builtin_amdgcn_mfma_f32_16x16x32_bf16(af[0][j], wf[1][ct][j], a, 0, 0, 0);
        a = __builtin_amdgcn_mfma_f32_16x16x32_bf16(af[1][j], wf[0][ct][j], a, 0, 0, 0);
        a = __builtin_amdgcn_mfma_f32_16x16x32_bf16(af[0][j], wf[2][ct][j], a, 0, 0, 0);
        a = __builtin_amdgcn_mfma_f32_16x16x32_bf16(af[2][j], wf[0][ct][j], a, 0, 0, 0);
        a = __builtin_amdgcn_mfma_f32_16x16x32_bf16(af[1][j], wf[1][ct][j], a, 0, 0, 0);
        acc[ct][s] = a;
      }
    }
    Cred[w][0][ln] = acc[0][0] + acc[0][1];
    Cred[w][1][ln] = acc[1][0] + acc[1][1];
    __syncthreads();
    if (tid < 128) {
      const int ct = tid >> 6, l2 = tid & 63;
      f32x4 sv = Cred[0][ct][l2] + Cred[1][ct][l2] + Cred[2][ct][l2] + Cred[3][ct][l2];
      float* dst = rw + p * kRW + matw * (kB * kD);
      const int col = col0 + ct * 16 + (l2 & 15);
      const int m0 = (l2 >> 4) * 4;  // C/D: col=lane&15, row=(lane>>4)*4+reg (m89)
#pragma unroll
      for (int r = 0; r < 4; ++r) atstf(&dst[(size_t)(m0 + r) * kD + col], sv[r]);
      // no drain, no flag: consumers validate the data itself
    }
    __syncthreads();  // keep: guards Cred reuse against compiler hoisting

    if (!tapeb) continue;

    // ---- P2 (tape blocks): poll rh/wv data directly (sentinel-validated) --
    const int b = g;
    float* rwp = rw + p * kRW;
    float* pr = &rwp[b * kD + d4];
    float* pw = &rwp[kB * kD + b * kD + d4];
    float4 rh4, wv4;
    for (;;) {
      U16 ur, uw;
      ur.ll[0] = atld8(pr); ur.ll[1] = atld8(pr + 2);
      uw.ll[0] = atld8(pw); uw.ll[1] = atld8(pw + 2);
      int bad = 0;
#pragma unroll
      for (int k2 = 0; k2 < 4; ++k2)
        bad |= (ur.wrd[k2] == kSentW) | (uw.wrd[k2] == kSentW);
      if (!bad) { rh4 = ur.f4; wv4 = uw.f4; break; }
      __builtin_amdgcn_s_sleep(1);
    }
    // re-poison this parity for its t+2 reuse (drained by the pre-marker
    // vmcnt(0) below, which orders it before the tag gating producers)
    atst8(pr, kSent); atst8(pr + 2, kSent);
    atst8(pw, kSent); atst8(pw + 2, kSent);

    // write-attention scores
    float part[kN];
#pragma unroll
    for (int n = 0; n < kN; ++n) {
      const float4 tv = *(const float4*)&tp[n][d4];
      part[n] = wv4.x * tv.x + wv4.y * tv.y + wv4.z * tv.z + wv4.w * tv.w;
    }
#pragma unroll
    for (int off = 32; off > 0; off >>= 1)
#pragma unroll
      for (int n = 0; n < kN; ++n) part[n] += __shfl_xor(part[n], off);
    if (ln == 0)
#pragma unroll
      for (int n = 0; n < kN; ++n) red2[w][n] = part[n];
    __syncthreads();

    float wa[kN];
    {
      float mx = -1e30f;
#pragma unroll
      for (int n = 0; n < kN; ++n) {
        const float sc = kScale * (red2[0][n] + red2[1][n] + red2[2][n] + red2[3][n]);
        wa[n] = sc;
        mx = fmaxf(mx, sc);
      }
      float ssum = 0.f;
#pragma unroll
      for (int n = 0; n < kN; ++n) { wa[n] = expf(wa[n] - mx); ssum += wa[n]; }
      const float inv = 1.f / ssum;
#pragma unroll
      for (int n = 0; n < kN; ++n) wa[n] *= inv;
    }

    // tape update (thread-local d-slice)
#pragma unroll
    for (int n = 0; n < kN; ++n) {
      float4 tv = *(const float4*)&tp[n][d4];
      const float wn = wa[n], om = 1.f - wn;
      tv.x = tv.x * om + wv4.x * wn; tv.y = tv.y * om + wv4.y * wn;
      tv.z = tv.z * om + wv4.z * wn; tv.w = tv.w * om + wv4.w * wn;
      *(float4*)&tp[n][d4] = tv;
    }

    if (t == kT - 1) {
#pragma unroll
      for (int n = 0; n < kN; ++n) {
        const float4 tv = *(const float4*)&tp[n][d4];
        *(float4*)&out_tape[((size_t)b * kN + n) * kD + d4] = tv;
      }
      *(float4*)&out_h[b * kD + d4] = hprev;
      continue;
    }

    // read-attention scores vs h(t)
#pragma unroll
    for (int n = 0; n < kN; ++n) {
      const float4 tv = *(const float4*)&tp[n][d4];
      part[n] = hprev.x * tv.x + hprev.y * tv.y + hprev.z * tv.z + hprev.w * tv.w;
    }
#pragma unroll
    for (int off = 32; off > 0; off >>= 1)
#pragma unroll
      for (int n = 0; n < kN; ++n) part[n] += __shfl_xor(part[n], off);
    if (ln == 0)
#pragma unroll
      for (int n = 0; n < kN; ++n) red2[w][8 + n] = part[n];
    __syncthreads();

    float ra[kN];
    {
      float mx = -1e30f;
#pragma unroll
      for (int n = 0; n < kN; ++n) {
        const float sc = kScale * (red2[0][8 + n] + red2[1][8 + n] + red2[2][8 + n] + red2[3][8 + n]);
        ra[n] = sc;
        mx = fmaxf(mx, sc);
      }
      float ssum = 0.f;
#pragma unroll
      for (int n = 0; n < kN; ++n) { ra[n] = expf(ra[n] - mx); ssum += ra[n]; }
      const float inv = 1.f / ssum;
#pragma unroll
      for (int n = 0; n < kN; ++n) ra[n] *= inv;
    }

    float4 rv = make_float4(0.f, 0.f, 0.f, 0.f);
#pragma unroll
    for (int n = 0; n < kN; ++n) {
      const float4 tv = *(const float4*)&tp[n][d4];
      rv.x += ra[n] * tv.x; rv.y += ra[n] * tv.y;
      rv.z += ra[n] * tv.z; rv.w += ra[n] * tv.w;
    }

    float4 hn;
    hn.x = tanhf(xp4.x + rh4.x + rv.x + bh4.x);
    hn.y = tanhf(xp4.y + rh4.y + rv.y + bh4.y);
    hn.z = tanhf(xp4.z + rh4.z + rv.z + bh4.z);
    hn.w = tanhf(xp4.w + rh4.w + rv.w + bh4.w);

    *(float4*)&hall[((size_t)b * kT + (t + 1)) * kD + d4] = hn;
    store_split(hsplit + (p ^ 1) * kHS, b, d4, hn);   // publish h(t+2)
    hprev = hn;

    // wave-local drain (covers splits + rw poisons), then bump the tag
    asm volatile("s_waitcnt vmcnt(0)" ::: "memory");
    if (ln == 0) atstu(&hmark[w * 16 + b], (unsigned)(t + 2));
  }
}

}  // namespace

extern "C" void kernel_launch(void* const* d_in, const int* in_sizes, int n_in,
                              void* d_out, int out_size, void* d_ws, size_t ws_size,
                              hipStream_t stream) {
  const float* x  = (const float*)d_in[0];
  const float* Wh = (const float*)d_in[1];
  const float* Wx = (const float*)d_in[2];
  const float* bh = (const float*)d_in[3];
  const float* Ww = (const float*)d_in[4];

  float* out = (float*)d_out;
  float* hall = out;                                  // [B,T,D]
  float* out_tape = out + (size_t)kB * kT * kD;       // [B,N,D]
  float* out_h = out_tape + (size_t)kB * kN * kD;     // [B,D]

  // ws: [0,4096) hmark tags; [4096, +192K) hsplit[2]; then rw[2] (256K).
  unsigned* hmark = (unsigned*)d_ws;
  unsigned short* hsplit = (unsigned short*)((char*)d_ws + 4096);
  float* rw = (float*)((char*)d_ws + 4096 + 2 * kHS * (int)sizeof(unsigned short));

  hipMemsetAsync(d_ws, 0, 4096, stream);                       // tags = 0
  hipMemsetAsync((void*)rw, 0xFF, 2 * kRW * sizeof(float), stream);  // poison

  xproj_kernel<<<dim3(kD / 128, (kB * kT) / 128), 256, 0, stream>>>(x, Wx, hall);

  scan_kernel<<<64, 256, 0, stream>>>(Wh, Ww, bh, hall, hsplit, rw, hmark,
                                      out_tape, out_h);
}

// Round 2
// 12463.752 us; speedup vs baseline: 1.1609x; 1.1609x over previous
//
#include <hip/hip_runtime.h>
#include <math.h>

typedef __bf16 bf16x8 __attribute__((ext_vector_type(8)));
typedef float f32x4 __attribute__((ext_vector_type(4)));

namespace {

constexpr int kB = 16;
constexpr int kT = 1024;
constexpr int kD = 1024;
constexpr int kN = 8;
constexpr float kScale = 0.03125f;  // 1/sqrt(1024)

constexpr unsigned long long kSent = ~0ull;      // 8B poison
constexpr unsigned kSentW = 0xFFFFFFFFu;         // 4B poison word (NaN)
constexpr int kHS = 3 * kB * kD;                 // shorts per h-split parity buf
constexpr int kRW = 2 * kB * kD;                 // floats per rw parity buf

__device__ inline unsigned short f2bf(float f) {  // RNE f32->bf16 bits
  unsigned u = __float_as_uint(f);
  u += 0x7FFFu + ((u >> 16) & 1u);
  return (unsigned short)(u >> 16);
}
__device__ inline float bf2f(unsigned short b) {
  return __uint_as_float(((unsigned)b) << 16);
}

// Fence-free cross-block transfer: relaxed agent-scope atomics compile to
// sc0|sc1 (L1+L2-bypass) accesses served by the device-coherent point.
__device__ inline void atst8(void* p, unsigned long long v) {
  __hip_atomic_store((unsigned long long*)p, v, __ATOMIC_RELAXED,
                     __HIP_MEMORY_SCOPE_AGENT);
}
__device__ inline unsigned long long atld8(const void* p) {
  return __hip_atomic_load((unsigned long long*)p, __ATOMIC_RELAXED,
                           __HIP_MEMORY_SCOPE_AGENT);
}
__device__ inline void atstf(float* p, float v) {
  __hip_atomic_store(p, v, __ATOMIC_RELAXED, __HIP_MEMORY_SCOPE_AGENT);
}
__device__ inline void atstu(unsigned* p, unsigned v) {
  __hip_atomic_store(p, v, __ATOMIC_RELAXED, __HIP_MEMORY_SCOPE_AGENT);
}
__device__ inline unsigned atldu(const unsigned* p) {
  return __hip_atomic_load((unsigned*)p, __ATOMIC_RELAXED,
                           __HIP_MEMORY_SCOPE_AGENT);
}

union U16 { unsigned long long ll[2]; unsigned wrd[4]; bf16x8 bv; float4 f4; };

// ---------------------------------------------------------------------------
// x_proj GEMM (round-1 proven): C[m,n] = sum_k X[m,k]*Wx[n,k]
__global__ __launch_bounds__(256)
void xproj_kernel(const float* __restrict__ X, const float* __restrict__ Wx,
                  float* __restrict__ C) {
  __shared__ float Xs[16][132];
  __shared__ float Ws[16][132];
  const int tid = threadIdx.x;
  const int n0 = blockIdx.x * 128;
  const int m0 = blockIdx.y * 128;
  const int tx = tid & 15;
  const int ty = tid >> 4;
  const int lr = tid >> 2;
  const int lc = (tid & 3) * 4;

  float acc[8][8];
#pragma unroll
  for (int i = 0; i < 8; ++i)
#pragma unroll
    for (int j = 0; j < 8; ++j) acc[i][j] = 0.f;

  for (int k0 = 0; k0 < kD; k0 += 16) {
    const float4 xa = *(const float4*)&X[(size_t)(m0 + lr) * kD + k0 + lc];
    const float4 xb = *(const float4*)&X[(size_t)(m0 + lr + 64) * kD + k0 + lc];
    const float4 wa = *(const float4*)&Wx[(size_t)(n0 + lr) * kD + k0 + lc];
    const float4 wb = *(const float4*)&Wx[(size_t)(n0 + lr + 64) * kD + k0 + lc];
    __syncthreads();
    Xs[lc + 0][lr] = xa.x; Xs[lc + 1][lr] = xa.y; Xs[lc + 2][lr] = xa.z; Xs[lc + 3][lr] = xa.w;
    Xs[lc + 0][lr + 64] = xb.x; Xs[lc + 1][lr + 64] = xb.y; Xs[lc + 2][lr + 64] = xb.z; Xs[lc + 3][lr + 64] = xb.w;
    Ws[lc + 0][lr] = wa.x; Ws[lc + 1][lr] = wa.y; Ws[lc + 2][lr] = wa.z; Ws[lc + 3][lr] = wa.w;
    Ws[lc + 0][lr + 64] = wb.x; Ws[lc + 1][lr + 64] = wb.y; Ws[lc + 2][lr + 64] = wb.z; Ws[lc + 3][lr + 64] = wb.w;
    __syncthreads();
#pragma unroll
    for (int k = 0; k < 16; ++k) {
      float a[8], b[8];
      *(float4*)&a[0] = *(const float4*)&Xs[k][ty * 8];
      *(float4*)&a[4] = *(const float4*)&Xs[k][ty * 8 + 4];
      *(float4*)&b[0] = *(const float4*)&Ws[k][tx * 8];
      *(float4*)&b[4] = *(const float4*)&Ws[k][tx * 8 + 4];
#pragma unroll
      for (int i = 0; i < 8; ++i)
#pragma unroll
        for (int j = 0; j < 8; ++j) acc[i][j] += a[i] * b[j];
    }
  }
#pragma unroll
  for (int i = 0; i < 8; ++i) {
    float4 v0 = make_float4(acc[i][0], acc[i][1], acc[i][2], acc[i][3]);
    float4 v1 = make_float4(acc[i][4], acc[i][5], acc[i][6], acc[i][7]);
    float* p = &C[(size_t)(m0 + ty * 8 + i) * kD + n0 + tx * 8];
    *(float4*)p = v0;
    *(float4*)(p + 4) = v1;
  }
}

// ---------------------------------------------------------------------------
__device__ inline void store_split(unsigned short* hs, int b, int d4, float4 h) {
  union { unsigned short u[4]; unsigned long long ll; } c2, c1, c0;
  float hv[4] = {h.x, h.y, h.z, h.w};
#pragma unroll
  for (int e = 0; e < 4; ++e) {
    unsigned short x = f2bf(hv[e]);
    float r = hv[e] - bf2f(x);
    unsigned short y = f2bf(r);
    float r2 = r - bf2f(y);
    unsigned short z = f2bf(r2);
    c2.u[e] = x; c1.u[e] = y; c0.u[e] = z;
  }
  atst8(&hs[0 * 16384 + b * kD + d4], c2.ll);
  atst8(&hs[1 * 16384 + b * kD + d4], c1.ll);
  atst8(&hs[2 * 16384 + b * kD + d4], c0.ll);
}

// ---------------------------------------------------------------------------
// Persistent scan, 64 blocks x 256 threads (all resident; deadlock-safe).
//
// Sync protocol (round-2: contention-fixed round-1):
//  * h broadcast: parity-double-buffered hsplit[2] + per-(batch,wave)
//    monotonic tags, ONE 64B CACHE LINE EACH (hmark[(w*16+b)*16]) -- round 1
//    packed 16 writer blocks into one line and paid line ping-pong. Producer
//    wave w of tape block b writes exactly the chunks consumer-wave w reads,
//    drains its own stores (s_waitcnt vmcnt(0)), lane 0 bumps the tag.
//    Consumers poll with 1 lane per 4-lane group + __shfl broadcast (4x
//    fewer load streams per line).
//  * rh/wv gather: parity-double-buffered rw[2] with DATA-AS-FLAG. Buffers
//    poisoned to 0xFFFFFFFF (NaN; unreachable by finite arithmetic).
//    Producers fire 4B stores -- no drain, no flag. The consumer's first
//    load IS the poll (validated per 32-bit word). Consumer re-poisons the
//    chunks it read; the poison is drained by the next publish's pre-tag
//    vmcnt(0), ordering it before the tag that gates producers (no ABA).
//  * Cred is parity double-buffered -> only ONE __syncthreads per GEMV
//    phase (write->read barrier); next iteration writes the other parity.
__global__ __launch_bounds__(256, 1)
void scan_kernel(const float* __restrict__ Wh, const float* __restrict__ Ww,
                 const float* __restrict__ bh,
                 float* __restrict__ hall,              // [B,T,D] xp -> h
                 unsigned short* __restrict__ hsplit,   // [2][3][16][1024] bf16
                 float* __restrict__ rw,                // [2][2][16][1024] f32
                 unsigned* __restrict__ hmark,          // [4][16] tags, 64B apart
                 float* __restrict__ out_tape,          // [B,N,D]
                 float* __restrict__ out_h) {           // [B,D]
  const int g = blockIdx.x;
  const int tid = threadIdx.x;
  const int w = tid >> 6;    // wave 0..3 (split-K: k range [256w, 256w+256))
  const int ln = tid & 63;
  const int bat = ln & 15;   // A-row (batch) / B-col selector
  const int q = ln >> 4;     // k-chunk selector
  const bool tapeb = (g < kB);
  const int col0 = (g & 31) * 32;
  const int matw = g >> 5;

  __shared__ float tp[kN][kD];          // 32 KiB (tape blocks)
  __shared__ f32x4 Cred[2][4][2][64];   // 16 KiB cross-wave C partials (dbuf)
  __shared__ float red2[4][16];

  // ---- weight prologue (plain loads; weights immutable) ----
  bf16x8 wf[3][2][8];
  {
    const float* Wsrc = matw ? Ww : Wh;
#pragma unroll
    for (int ct = 0; ct < 2; ++ct)
#pragma unroll
      for (int j = 0; j < 8; ++j) {
        const float* src = &Wsrc[(size_t)(col0 + ct * 16 + bat) * kD + (w * 8 + j) * 32 + q * 8];
        float v[8];
        *(float4*)&v[0] = *(const float4*)src;
        *(float4*)&v[4] = *(const float4*)(src + 4);
        union { unsigned short u[8]; bf16x8 b; } e2, e1, e0;
#pragma unroll
        for (int e = 0; e < 8; ++e) {
          unsigned short a = f2bf(v[e]);
          float r = v[e] - bf2f(a);
          unsigned short b2 = f2bf(r);
          float r2 = r - bf2f(b2);
          unsigned short c = f2bf(r2);
          e2.u[e] = a; e1.u[e] = b2; e0.u[e] = c;
        }
        wf[0][ct][j] = e2.b;
        wf[1][ct][j] = e1.b;
        wf[2][ct][j] = e0.b;
      }
  }

  // ---- tape-block bootstrap: tape=0, h(1)=tanh(xp0), publish parity 0 ----
  float4 hprev = make_float4(0.f, 0.f, 0.f, 0.f);
  float4 bh4 = make_float4(0.f, 0.f, 0.f, 0.f);
  const int d4 = tid * 4;
  if (tapeb) {
    const size_t x0 = (size_t)g * kT * kD + d4;
    float4 xp0 = *(const float4*)&hall[x0];
    hprev.x = tanhf(xp0.x); hprev.y = tanhf(xp0.y);
    hprev.z = tanhf(xp0.z); hprev.w = tanhf(xp0.w);
    *(float4*)&hall[x0] = hprev;
    store_split(hsplit, g, d4, hprev);           // parity 0 = h(1)
    asm volatile("s_waitcnt vmcnt(0)" ::: "memory");  // wave-local drain
    if (ln == 0) atstu(&hmark[(w * 16 + g) * 16], 1u);  // tag 1: h(1) ready
    bh4 = *(const float4*)&bh[d4];
    float4 z = make_float4(0.f, 0.f, 0.f, 0.f);
#pragma unroll
    for (int i = 0; i < 8; ++i) ((float4*)&tp[0][0])[i * 256 + tid] = z;
    __syncthreads();
  }

  for (int t = 0; t < kT; ++t) {
    const int p = t & 1;
    const unsigned short* hb = hsplit + p * kHS;

    // xp prefetch at the very top: HBM latency hides under the GEMV phase
    float4 xp4 = make_float4(0.f, 0.f, 0.f, 0.f);
    if (tapeb && t < kT - 1)
      xp4 = *(const float4*)&hall[((size_t)g * kT + (t + 1)) * kD + d4];

    // ---- phase 1: spin on h tag (1 poller per 4-lane group + shfl bcast) --
    {
      const unsigned need = (unsigned)(t + 1);
      const unsigned* mk = &hmark[(w * 16 + bat) * 16];
      for (;;) {
        unsigned v = 0;
        if (q == 0) v = atldu(mk);
        v = __shfl(v, bat);              // broadcast from the q==0 lane
        if (v >= need) break;
        __builtin_amdgcn_s_sleep(1);
      }
    }
    bf16x8 af[3][8];
#pragma unroll
    for (int j = 0; j < 8; ++j) {
      const unsigned short* p0 = &hb[bat * kD + w * 256 + j * 32 + q * 8];
#pragma unroll
      for (int part = 0; part < 3; ++part) {
        U16 u;
        u.ll[0] = atld8(p0 + part * 16384);
        u.ll[1] = atld8(p0 + part * 16384 + 4);
        af[part][j] = u.bv;
      }
    }

    // ---- 6-product triple-split MFMA ----
    f32x4 zf = {0.f, 0.f, 0.f, 0.f};
    f32x4 acc[2][2] = {{zf, zf}, {zf, zf}};
#pragma unroll
    for (int j = 0; j < 8; ++j) {
      const int s = j & 1;
#pragma unroll
      for (int ct = 0; ct < 2; ++ct) {
        f32x4 a = acc[ct][s];
        a = __builtin_amdgcn_mfma_f32_16x16x32_bf16(af[0][j], wf[0][ct][j], a, 0, 0, 0);
        a = __builtin_amdgcn_mfma_f32_16x16x32_bf16(af[0][j], wf[1][ct][j], a, 0, 0, 0);
        a = __builtin_amdgcn_mfma_f32_16x16x32_bf16(af[1][j], wf[0][ct][j], a, 0, 0, 0);
        a = __builtin_amdgcn_mfma_f32_16x16x32_bf16(af[0][j], wf[2][ct][j], a, 0, 0, 0);
        a = __builtin_amdgcn_mfma_f32_16x16x32_bf16(af[2][j], wf[0][ct][j], a, 0, 0, 0);
        a = __builtin_amdgcn_mfma_f32_16x16x32_bf16(af[1][j], wf[1][ct][j], a, 0, 0, 0);
        acc[ct][s] = a;
      }
    }
    Cred[p][w][0][ln] = acc[0][0] + acc[0][1];
    Cred[p][w][1][ln] = acc[1][0] + acc[1][1];
    __syncthreads();
    if (tid < 128) {
      const int ct = tid >> 6, l2 = tid & 63;
      f32x4 sv = Cred[p][0][ct][l2] + Cred[p][1][ct][l2] +
                 Cred[p][2][ct][l2] + Cred[p][3][ct][l2];
      float* dst = rw + p * kRW + matw * (kB * kD);
      const int col = col0 + ct * 16 + (l2 & 15);
      const int m0 = (l2 >> 4) * 4;  // C/D: col=lane&15, row=(lane>>4)*4+reg (m89)
#pragma unroll
      for (int r = 0; r < 4; ++r) atstf(&dst[(size_t)(m0 + r) * kD + col], sv[r]);
      // no drain, no flag: consumers validate the data itself
    }
    // no second barrier: next iteration writes Cred[p^1]

    if (!tapeb) continue;

    // ---- P2 (tape blocks): poll rh/wv data directly (sentinel-validated) --
    const int b = g;
    float* rwp = rw + p * kRW;
    float* pr = &rwp[b * kD + d4];
    float* pw = &rwp[kB * kD + b * kD + d4];
    float4 rh4, wv4;
    for (;;) {
      U16 ur, uw;
      ur.ll[0] = atld8(pr); ur.ll[1] = atld8(pr + 2);
      uw.ll[0] = atld8(pw); uw.ll[1] = atld8(pw + 2);
      int bad = 0;
#pragma unroll
      for (int k2 = 0; k2 < 4; ++k2)
        bad |= (ur.wrd[k2] == kSentW) | (uw.wrd[k2] == kSentW);
      if (!bad) { rh4 = ur.f4; wv4 = uw.f4; break; }
      __builtin_amdgcn_s_sleep(1);
    }
    // re-poison this parity for its t+2 reuse (drained by the pre-tag
    // vmcnt(0) below, which orders it before the tag gating producers)
    atst8(pr, kSent); atst8(pr + 2, kSent);
    atst8(pw, kSent); atst8(pw + 2, kSent);

    // write-attention scores
    float part[kN];
#pragma unroll
    for (int n = 0; n < kN; ++n) {
      const float4 tv = *(const float4*)&tp[n][d4];
      part[n] = wv4.x * tv.x + wv4.y * tv.y + wv4.z * tv.z + wv4.w * tv.w;
    }
#pragma unroll
    for (int off = 32; off > 0; off >>= 1)
#pragma unroll
      for (int n = 0; n < kN; ++n) part[n] += __shfl_xor(part[n], off);
    if (ln == 0)
#pragma unroll
      for (int n = 0; n < kN; ++n) red2[w][n] = part[n];
    __syncthreads();

    float wa[kN];
    {
      float mx = -1e30f;
#pragma unroll
      for (int n = 0; n < kN; ++n) {
        const float sc = kScale * (red2[0][n] + red2[1][n] + red2[2][n] + red2[3][n]);
        wa[n] = sc;
        mx = fmaxf(mx, sc);
      }
      float ssum = 0.f;
#pragma unroll
      for (int n = 0; n < kN; ++n) { wa[n] = expf(wa[n] - mx); ssum += wa[n]; }
      const float inv = 1.f / ssum;
#pragma unroll
      for (int n = 0; n < kN; ++n) wa[n] *= inv;
    }

    // tape update (thread-local d-slice)
#pragma unroll
    for (int n = 0; n < kN; ++n) {
      float4 tv = *(const float4*)&tp[n][d4];
      const float wn = wa[n], om = 1.f - wn;
      tv.x = tv.x * om + wv4.x * wn; tv.y = tv.y * om + wv4.y * wn;
      tv.z = tv.z * om + wv4.z * wn; tv.w = tv.w * om + wv4.w * wn;
      *(float4*)&tp[n][d4] = tv;
    }

    if (t == kT - 1) {
#pragma unroll
      for (int n = 0; n < kN; ++n) {
        const float4 tv = *(const float4*)&tp[n][d4];
        *(float4*)&out_tape[((size_t)b * kN + n) * kD + d4] = tv;
      }
      *(float4*)&out_h[b * kD + d4] = hprev;
      continue;
    }

    // read-attention scores vs h(t)
#pragma unroll
    for (int n = 0; n < kN; ++n) {
      const float4 tv = *(const float4*)&tp[n][d4];
      part[n] = hprev.x * tv.x + hprev.y * tv.y + hprev.z * tv.z + hprev.w * tv.w;
    }
#pragma unroll
    for (int off = 32; off > 0; off >>= 1)
#pragma unroll
      for (int n = 0; n < kN; ++n) part[n] += __shfl_xor(part[n], off);
    if (ln == 0)
#pragma unroll
      for (int n = 0; n < kN; ++n) red2[w][8 + n] = part[n];
    __syncthreads();

    float ra[kN];
    {
      float mx = -1e30f;
#pragma unroll
      for (int n = 0; n < kN; ++n) {
        const float sc = kScale * (red2[0][8 + n] + red2[1][8 + n] + red2[2][8 + n] + red2[3][8 + n]);
        ra[n] = sc;
        mx = fmaxf(mx, sc);
      }
      float ssum = 0.f;
#pragma unroll
      for (int n = 0; n < kN; ++n) { ra[n] = expf(ra[n] - mx); ssum += ra[n]; }
      const float inv = 1.f / ssum;
#pragma unroll
      for (int n = 0; n < kN; ++n) ra[n] *= inv;
    }

    float4 rv = make_float4(0.f, 0.f, 0.f, 0.f);
#pragma unroll
    for (int n = 0; n < kN; ++n) {
      const float4 tv = *(const float4*)&tp[n][d4];
      rv.x += ra[n] * tv.x; rv.y += ra[n] * tv.y;
      rv.z += ra[n] * tv.z; rv.w += ra[n] * tv.w;
    }

    float4 hn;
    hn.x = tanhf(xp4.x + rh4.x + rv.x + bh4.x);
    hn.y = tanhf(xp4.y + rh4.y + rv.y + bh4.y);
    hn.z = tanhf(xp4.z + rh4.z + rv.z + bh4.z);
    hn.w = tanhf(xp4.w + rh4.w + rv.w + bh4.w);

    *(float4*)&hall[((size_t)b * kT + (t + 1)) * kD + d4] = hn;
    store_split(hsplit + (p ^ 1) * kHS, b, d4, hn);   // publish h(t+2)
    hprev = hn;

    // wave-local drain (covers splits + rw poisons), then bump the tag
    asm volatile("s_waitcnt vmcnt(0)" ::: "memory");
    if (ln == 0) atstu(&hmark[(w * 16 + b) * 16], (unsigned)(t + 2));
  }
}

}  // namespace

extern "C" void kernel_launch(void* const* d_in, const int* in_sizes, int n_in,
                              void* d_out, int out_size, void* d_ws, size_t ws_size,
                              hipStream_t stream) {
  const float* x  = (const float*)d_in[0];
  const float* Wh = (const float*)d_in[1];
  const float* Wx = (const float*)d_in[2];
  const float* bh = (const float*)d_in[3];
  const float* Ww = (const float*)d_in[4];

  float* out = (float*)d_out;
  float* hall = out;                                  // [B,T,D]
  float* out_tape = out + (size_t)kB * kT * kD;       // [B,N,D]
  float* out_h = out_tape + (size_t)kB * kN * kD;     // [B,D]

  // ws: [0,4096) hmark tags (64 x 64B lines); [4096,+192K) hsplit[2]; rw[2].
  unsigned* hmark = (unsigned*)d_ws;
  unsigned short* hsplit = (unsigned short*)((char*)d_ws + 4096);
  float* rw = (float*)((char*)d_ws + 4096 + 2 * kHS * (int)sizeof(unsigned short));

  hipMemsetAsync(d_ws, 0, 4096, stream);                             // tags = 0
  hipMemsetAsync((void*)rw, 0xFF, 2 * kRW * sizeof(float), stream);  // poison

  xproj_kernel<<<dim3(kD / 128, (kB * kT) / 128), 256, 0, stream>>>(x, Wx, hall);

  scan_kernel<<<64, 256, 0, stream>>>(Wh, Ww, bh, hall, hsplit, rw, hmark,
                                      out_tape, out_h);
}

// Round 4
// 10795.036 us; speedup vs baseline: 1.3404x; 1.1546x over previous
//
#include <hip/hip_runtime.h>
#include <math.h>

typedef __bf16 bf16x8 __attribute__((ext_vector_type(8)));
typedef float f32x4 __attribute__((ext_vector_type(4)));

namespace {

constexpr int kB = 16;
constexpr int kT = 1024;
constexpr int kD = 1024;
constexpr int kN = 8;
constexpr float kScale = 0.03125f;  // 1/sqrt(1024)

constexpr unsigned long long kSent = ~0ull;      // 8B poison
constexpr unsigned kSentW = 0xFFFFFFFFu;         // 4B poison word (NaN)
constexpr int kHS = 3 * kB * kD;                 // shorts per h-split parity buf
constexpr int kRW = 2 * kB * kD;                 // floats per rw parity buf

__device__ inline unsigned short f2bf(float f) {  // RNE f32->bf16 bits
  unsigned u = __float_as_uint(f);
  u += 0x7FFFu + ((u >> 16) & 1u);
  return (unsigned short)(u >> 16);
}
__device__ inline float bf2f(unsigned short b) {
  return __uint_as_float(((unsigned)b) << 16);
}

// Fence-free cross-block transfer: relaxed agent-scope atomics compile to
// sc0|sc1 (L1+L2-bypass) accesses served by the device-coherent point.
__device__ inline void atst8(void* p, unsigned long long v) {
  __hip_atomic_store((unsigned long long*)p, v, __ATOMIC_RELAXED,
                     __HIP_MEMORY_SCOPE_AGENT);
}
__device__ inline unsigned long long atld8(const void* p) {
  return __hip_atomic_load((unsigned long long*)p, __ATOMIC_RELAXED,
                           __HIP_MEMORY_SCOPE_AGENT);
}
__device__ inline void atstf(float* p, float v) {
  __hip_atomic_store(p, v, __ATOMIC_RELAXED, __HIP_MEMORY_SCOPE_AGENT);
}
__device__ inline void atstu(unsigned* p, unsigned v) {
  __hip_atomic_store(p, v, __ATOMIC_RELAXED, __HIP_MEMORY_SCOPE_AGENT);
}
__device__ inline unsigned atldu(const unsigned* p) {
  return __hip_atomic_load((unsigned*)p, __ATOMIC_RELAXED,
                           __HIP_MEMORY_SCOPE_AGENT);
}

union U16 { unsigned long long ll[2]; unsigned wrd[4]; bf16x8 bv; float4 f4; };

// ---------------------------------------------------------------------------
// x_proj GEMM (round-1 proven): C[m,n] = sum_k X[m,k]*Wx[n,k]
__global__ __launch_bounds__(256)
void xproj_kernel(const float* __restrict__ X, const float* __restrict__ Wx,
                  float* __restrict__ C) {
  __shared__ float Xs[16][132];
  __shared__ float Ws[16][132];
  const int tid = threadIdx.x;
  const int n0 = blockIdx.x * 128;
  const int m0 = blockIdx.y * 128;
  const int tx = tid & 15;
  const int ty = tid >> 4;
  const int lr = tid >> 2;
  const int lc = (tid & 3) * 4;

  float acc[8][8];
#pragma unroll
  for (int i = 0; i < 8; ++i)
#pragma unroll
    for (int j = 0; j < 8; ++j) acc[i][j] = 0.f;

  for (int k0 = 0; k0 < kD; k0 += 16) {
    const float4 xa = *(const float4*)&X[(size_t)(m0 + lr) * kD + k0 + lc];
    const float4 xb = *(const float4*)&X[(size_t)(m0 + lr + 64) * kD + k0 + lc];
    const float4 wa = *(const float4*)&Wx[(size_t)(n0 + lr) * kD + k0 + lc];
    const float4 wb = *(const float4*)&Wx[(size_t)(n0 + lr + 64) * kD + k0 + lc];
    __syncthreads();
    Xs[lc + 0][lr] = xa.x; Xs[lc + 1][lr] = xa.y; Xs[lc + 2][lr] = xa.z; Xs[lc + 3][lr] = xa.w;
    Xs[lc + 0][lr + 64] = xb.x; Xs[lc + 1][lr + 64] = xb.y; Xs[lc + 2][lr + 64] = xb.z; Xs[lc + 3][lr + 64] = xb.w;
    Ws[lc + 0][lr] = wa.x; Ws[lc + 1][lr] = wa.y; Ws[lc + 2][lr] = wa.z; Ws[lc + 3][lr] = wa.w;
    Ws[lc + 0][lr + 64] = wb.x; Ws[lc + 1][lr + 64] = wb.y; Ws[lc + 2][lr + 64] = wb.z; Ws[lc + 3][lr + 64] = wb.w;
    __syncthreads();
#pragma unroll
    for (int k = 0; k < 16; ++k) {
      float a[8], b[8];
      *(float4*)&a[0] = *(const float4*)&Xs[k][ty * 8];
      *(float4*)&a[4] = *(const float4*)&Xs[k][ty * 8 + 4];
      *(float4*)&b[0] = *(const float4*)&Ws[k][tx * 8];
      *(float4*)&b[4] = *(const float4*)&Ws[k][tx * 8 + 4];
#pragma unroll
      for (int i = 0; i < 8; ++i)
#pragma unroll
        for (int j = 0; j < 8; ++j) acc[i][j] += a[i] * b[j];
    }
  }
#pragma unroll
  for (int i = 0; i < 8; ++i) {
    float4 v0 = make_float4(acc[i][0], acc[i][1], acc[i][2], acc[i][3]);
    float4 v1 = make_float4(acc[i][4], acc[i][5], acc[i][6], acc[i][7]);
    float* p = &C[(size_t)(m0 + ty * 8 + i) * kD + n0 + tx * 8];
    *(float4*)p = v0;
    *(float4*)(p + 4) = v1;
  }
}

// ---------------------------------------------------------------------------
// h-split store, CONSUMER-LANE-MAJOR layout (round-3, re-certified):
// element (part, w, j, half, l) lives at short-offset
//   part*16384 + ((w*8+j)<<9) + (half<<8) + l*4,   l = q*16 + batch.
// A consumer wave's 64 lanes read dense 8B-stride runs (8 cache lines per
// instruction instead of 64 scattered 2KB-apart segments). Pure address
// permutation; fragment contents bit-identical to the row-major layout.
__device__ inline void store_split(unsigned short* hs, int b, int d4, float4 h) {
  union { unsigned short u[4]; unsigned long long ll; } c2, c1, c0;
  float hv[4] = {h.x, h.y, h.z, h.w};
#pragma unroll
  for (int e = 0; e < 4; ++e) {
    unsigned short x = f2bf(hv[e]);
    float r = hv[e] - bf2f(x);
    unsigned short y = f2bf(r);
    float r2 = r - bf2f(y);
    unsigned short z = f2bf(r2);
    c2.u[e] = x; c1.u[e] = y; c0.u[e] = z;
  }
  const int w = d4 >> 8;
  const int j = (d4 >> 5) & 7;
  const int q = (d4 >> 3) & 3;
  const int hf = (d4 >> 2) & 1;
  const int off = ((w * 8 + j) << 9) + (hf << 8) + ((q * 16 + b) << 2);
  atst8(&hs[0 * 16384 + off], c2.ll);
  atst8(&hs[1 * 16384 + off], c1.ll);
  atst8(&hs[2 * 16384 + off], c0.ll);
}

// ---------------------------------------------------------------------------
// Persistent scan, 64 blocks x 256 threads (all resident; deadlock-safe).
//
// Round-4: round-3's permuted h layout, with the round-3 hall-store
// reordering REVERTED (it failed the post-timing re-check: a replay-timing
// race). The hall h-store is back INSIDE the drained publish section, as in
// round 2, which passed post-timing. Compiler fences re-added after both
// poll loops (round-0 provenance): forbid sinking/hoisting the dependent
// loads across the spins.
//
//  * h broadcast: parity-double-buffered hsplit[2] + per-(batch,wave)
//    monotonic tags, one 64B cache line each (hmark[(w*16+b)*16]). Producer
//    wave w of tape block b writes exactly the chunks consumer-wave w reads,
//    drains its own stores (s_waitcnt vmcnt(0)), lane 0 bumps the tag.
//    Consumers poll with 1 lane per 4-lane group + __shfl broadcast.
//  * rh/wv gather: parity-double-buffered rw[2] with DATA-AS-FLAG. Buffers
//    poisoned to 0xFFFFFFFF (NaN; unreachable by finite arithmetic).
//    Producers fire 4B stores -- no drain, no flag. The consumer's first
//    load IS the poll (validated per 32-bit word). Consumer re-poisons the
//    chunks it read; the poison is drained by the next publish's pre-tag
//    vmcnt(0), ordering it before the tag that gates producers (no ABA).
//  * Cred is parity double-buffered -> only ONE __syncthreads per GEMV
//    phase; next iteration writes the other parity.
__global__ __launch_bounds__(256, 1)
void scan_kernel(const float* __restrict__ Wh, const float* __restrict__ Ww,
                 const float* __restrict__ bh,
                 float* __restrict__ hall,              // [B,T,D] xp -> h
                 unsigned short* __restrict__ hsplit,   // [2][3][4][8][512] bf16
                 float* __restrict__ rw,                // [2][2][16][1024] f32
                 unsigned* __restrict__ hmark,          // [4][16] tags, 64B apart
                 float* __restrict__ out_tape,          // [B,N,D]
                 float* __restrict__ out_h) {           // [B,D]
  const int g = blockIdx.x;
  const int tid = threadIdx.x;
  const int w = tid >> 6;    // wave 0..3 (split-K: k range [256w, 256w+256))
  const int ln = tid & 63;
  const int bat = ln & 15;   // A-row (batch) / B-col selector
  const int q = ln >> 4;     // k-chunk selector
  const bool tapeb = (g < kB);
  const int col0 = (g & 31) * 32;
  const int matw = g >> 5;

  __shared__ float tp[kN][kD];          // 32 KiB (tape blocks)
  __shared__ f32x4 Cred[2][4][2][64];   // 16 KiB cross-wave C partials (dbuf)
  __shared__ float red2[4][16];

  // ---- weight prologue (plain loads; weights immutable) ----
  bf16x8 wf[3][2][8];
  {
    const float* Wsrc = matw ? Ww : Wh;
#pragma unroll
    for (int ct = 0; ct < 2; ++ct)
#pragma unroll
      for (int j = 0; j < 8; ++j) {
        const float* src = &Wsrc[(size_t)(col0 + ct * 16 + bat) * kD + (w * 8 + j) * 32 + q * 8];
        float v[8];
        *(float4*)&v[0] = *(const float4*)src;
        *(float4*)&v[4] = *(const float4*)(src + 4);
        union { unsigned short u[8]; bf16x8 b; } e2, e1, e0;
#pragma unroll
        for (int e = 0; e < 8; ++e) {
          unsigned short a = f2bf(v[e]);
          float r = v[e] - bf2f(a);
          unsigned short b2 = f2bf(r);
          float r2 = r - bf2f(b2);
          unsigned short c = f2bf(r2);
          e2.u[e] = a; e1.u[e] = b2; e0.u[e] = c;
        }
        wf[0][ct][j] = e2.b;
        wf[1][ct][j] = e1.b;
        wf[2][ct][j] = e0.b;
      }
  }

  // ---- tape-block bootstrap: tape=0, h(1)=tanh(xp0), publish parity 0 ----
  float4 hprev = make_float4(0.f, 0.f, 0.f, 0.f);
  float4 bh4 = make_float4(0.f, 0.f, 0.f, 0.f);
  const int d4 = tid * 4;
  if (tapeb) {
    const size_t x0 = (size_t)g * kT * kD + d4;
    float4 xp0 = *(const float4*)&hall[x0];
    hprev.x = tanhf(xp0.x); hprev.y = tanhf(xp0.y);
    hprev.z = tanhf(xp0.z); hprev.w = tanhf(xp0.w);
    *(float4*)&hall[x0] = hprev;
    store_split(hsplit, g, d4, hprev);           // parity 0 = h(1)
    asm volatile("s_waitcnt vmcnt(0)" ::: "memory");  // wave-local drain
    if (ln == 0) atstu(&hmark[(w * 16 + g) * 16], 1u);  // tag 1: h(1) ready
    bh4 = *(const float4*)&bh[d4];
    float4 z = make_float4(0.f, 0.f, 0.f, 0.f);
#pragma unroll
    for (int i = 0; i < 8; ++i) ((float4*)&tp[0][0])[i * 256 + tid] = z;
    __syncthreads();
  }

  for (int t = 0; t < kT; ++t) {
    const int p = t & 1;
    const unsigned short* hb = hsplit + p * kHS;

    // xp prefetch at the very top: HBM latency hides under the GEMV phase
    float4 xp4 = make_float4(0.f, 0.f, 0.f, 0.f);
    if (tapeb && t < kT - 1)
      xp4 = *(const float4*)&hall[((size_t)g * kT + (t + 1)) * kD + d4];

    // ---- phase 1: spin on h tag (1 poller per 4-lane group + shfl bcast) --
    {
      const unsigned need = (unsigned)(t + 1);
      const unsigned* mk = &hmark[(w * 16 + bat) * 16];
      for (;;) {
        unsigned v = 0;
        if (q == 0) v = atldu(mk);
        v = __shfl(v, bat);              // broadcast from the q==0 lane
        if (v >= need) break;
        __builtin_amdgcn_s_sleep(1);
      }
      asm volatile("" ::: "memory");     // no load sinks above this point
    }
    // A fragments: dense lane-major reads (permuted layout)
    bf16x8 af[3][8];
    const unsigned short* hw0 = hb + (w << 12) + (ln << 2);  // w*4096 + ln*4
#pragma unroll
    for (int j = 0; j < 8; ++j) {
      const unsigned short* p0 = hw0 + (j << 9);
#pragma unroll
      for (int part = 0; part < 3; ++part) {
        U16 u;
        u.ll[0] = atld8(p0 + part * 16384);
        u.ll[1] = atld8(p0 + part * 16384 + 256);
        af[part][j] = u.bv;
      }
    }

    // ---- 6-product triple-split MFMA ----
    f32x4 zf = {0.f, 0.f, 0.f, 0.f};
    f32x4 acc[2][2] = {{zf, zf}, {zf, zf}};
#pragma unroll
    for (int j = 0; j < 8; ++j) {
      const int s = j & 1;
#pragma unroll
      for (int ct = 0; ct < 2; ++ct) {
        f32x4 a = acc[ct][s];
        a = __builtin_amdgcn_mfma_f32_16x16x32_bf16(af[0][j], wf[0][ct][j], a, 0, 0, 0);
        a = __builtin_amdgcn_mfma_f32_16x16x32_bf16(af[0][j], wf[1][ct][j], a, 0, 0, 0);
        a = __builtin_amdgcn_mfma_f32_16x16x32_bf16(af[1][j], wf[0][ct][j], a, 0, 0, 0);
        a = __builtin_amdgcn_mfma_f32_16x16x32_bf16(af[0][j], wf[2][ct][j], a, 0, 0, 0);
        a = __builtin_amdgcn_mfma_f32_16x16x32_bf16(af[2][j], wf[0][ct][j], a, 0, 0, 0);
        a = __builtin_amdgcn_mfma_f32_16x16x32_bf16(af[1][j], wf[1][ct][j], a, 0, 0, 0);
        acc[ct][s] = a;
      }
    }
    Cred[p][w][0][ln] = acc[0][0] + acc[0][1];
    Cred[p][w][1][ln] = acc[1][0] + acc[1][1];
    __syncthreads();
    if (tid < 128) {
      const int ct = tid >> 6, l2 = tid & 63;
      f32x4 sv = Cred[p][0][ct][l2] + Cred[p][1][ct][l2] +
                 Cred[p][2][ct][l2] + Cred[p][3][ct][l2];
      float* dst = rw + p * kRW + matw * (kB * kD);
      const int col = col0 + ct * 16 + (l2 & 15);
      const int m0 = (l2 >> 4) * 4;  // C/D: col=lane&15, row=(lane>>4)*4+reg (m89)
#pragma unroll
      for (int r = 0; r < 4; ++r) atstf(&dst[(size_t)(m0 + r) * kD + col], sv[r]);
      // no drain, no flag: consumers validate the data itself
    }
    // no second barrier: next iteration writes Cred[p^1]

    if (!tapeb) continue;

    // ---- P2 (tape blocks): poll rh/wv data directly (sentinel-validated) --
    const int b = g;
    float* rwp = rw + p * kRW;
    float* pr = &rwp[b * kD + d4];
    float* pw = &rwp[kB * kD + b * kD + d4];
    float4 rh4, wv4;
    for (;;) {
      U16 ur, uw;
      ur.ll[0] = atld8(pr); ur.ll[1] = atld8(pr + 2);
      uw.ll[0] = atld8(pw); uw.ll[1] = atld8(pw + 2);
      int bad = 0;
#pragma unroll
      for (int k2 = 0; k2 < 4; ++k2)
        bad |= (ur.wrd[k2] == kSentW) | (uw.wrd[k2] == kSentW);
      if (!bad) { rh4 = ur.f4; wv4 = uw.f4; break; }
      __builtin_amdgcn_s_sleep(1);
    }
    asm volatile("" ::: "memory");       // no reorder across the data-poll
    // re-poison this parity for its t+2 reuse (drained by the pre-tag
    // vmcnt(0) below, which orders it before the tag gating producers)
    atst8(pr, kSent); atst8(pr + 2, kSent);
    atst8(pw, kSent); atst8(pw + 2, kSent);

    // write-attention scores
    float part[kN];
#pragma unroll
    for (int n = 0; n < kN; ++n) {
      const float4 tv = *(const float4*)&tp[n][d4];
      part[n] = wv4.x * tv.x + wv4.y * tv.y + wv4.z * tv.z + wv4.w * tv.w;
    }
#pragma unroll
    for (int off = 32; off > 0; off >>= 1)
#pragma unroll
      for (int n = 0; n < kN; ++n) part[n] += __shfl_xor(part[n], off);
    if (ln == 0)
#pragma unroll
      for (int n = 0; n < kN; ++n) red2[w][n] = part[n];
    __syncthreads();

    float wa[kN];
    {
      float mx = -1e30f;
#pragma unroll
      for (int n = 0; n < kN; ++n) {
        const float sc = kScale * (red2[0][n] + red2[1][n] + red2[2][n] + red2[3][n]);
        wa[n] = sc;
        mx = fmaxf(mx, sc);
      }
      float ssum = 0.f;
#pragma unroll
      for (int n = 0; n < kN; ++n) { wa[n] = expf(wa[n] - mx); ssum += wa[n]; }
      const float inv = 1.f / ssum;
#pragma unroll
      for (int n = 0; n < kN; ++n) wa[n] *= inv;
    }

    // tape update (thread-local d-slice)
#pragma unroll
    for (int n = 0; n < kN; ++n) {
      float4 tv = *(const float4*)&tp[n][d4];
      const float wn = wa[n], om = 1.f - wn;
      tv.x = tv.x * om + wv4.x * wn; tv.y = tv.y * om + wv4.y * wn;
      tv.z = tv.z * om + wv4.z * wn; tv.w = tv.w * om + wv4.w * wn;
      *(float4*)&tp[n][d4] = tv;
    }

    if (t == kT - 1) {
#pragma unroll
      for (int n = 0; n < kN; ++n) {
        const float4 tv = *(const float4*)&tp[n][d4];
        *(float4*)&out_tape[((size_t)b * kN + n) * kD + d4] = tv;
      }
      *(float4*)&out_h[b * kD + d4] = hprev;
      continue;
    }

    // read-attention scores vs h(t)
#pragma unroll
    for (int n = 0; n < kN; ++n) {
      const float4 tv = *(const float4*)&tp[n][d4];
      part[n] = hprev.x * tv.x + hprev.y * tv.y + hprev.z * tv.z + hprev.w * tv.w;
    }
#pragma unroll
    for (int off = 32; off > 0; off >>= 1)
#pragma unroll
      for (int n = 0; n < kN; ++n) part[n] += __shfl_xor(part[n], off);
    if (ln == 0)
#pragma unroll
      for (int n = 0; n < kN; ++n) red2[w][8 + n] = part[n];
    __syncthreads();

    float ra[kN];
    {
      float mx = -1e30f;
#pragma unroll
      for (int n = 0; n < kN; ++n) {
        const float sc = kScale * (red2[0][8 + n] + red2[1][8 + n] + red2[2][8 + n] + red2[3][8 + n]);
        ra[n] = sc;
        mx = fmaxf(mx, sc);
      }
      float ssum = 0.f;
#pragma unroll
      for (int n = 0; n < kN; ++n) { ra[n] = expf(ra[n] - mx); ssum += ra[n]; }
      const float inv = 1.f / ssum;
#pragma unroll
      for (int n = 0; n < kN; ++n) ra[n] *= inv;
    }

    float4 rv = make_float4(0.f, 0.f, 0.f, 0.f);
#pragma unroll
    for (int n = 0; n < kN; ++n) {
      const float4 tv = *(const float4*)&tp[n][d4];
      rv.x += ra[n] * tv.x; rv.y += ra[n] * tv.y;
      rv.z += ra[n] * tv.z; rv.w += ra[n] * tv.w;
    }

    float4 hn;
    hn.x = tanhf(xp4.x + rh4.x + rv.x + bh4.x);
    hn.y = tanhf(xp4.y + rh4.y + rv.y + bh4.y);
    hn.z = tanhf(xp4.z + rh4.z + rv.z + bh4.z);
    hn.w = tanhf(xp4.w + rh4.w + rv.w + bh4.w);

    // publish section (round-2 order, post-timing-proven): hall store +
    // splits all inside the drain, then the tag.
    *(float4*)&hall[((size_t)b * kT + (t + 1)) * kD + d4] = hn;
    store_split(hsplit + (p ^ 1) * kHS, b, d4, hn);   // publish h(t+2)
    hprev = hn;

    // wave-local drain (covers hall + splits + rw poisons), then the tag
    asm volatile("s_waitcnt vmcnt(0)" ::: "memory");
    if (ln == 0) atstu(&hmark[(w * 16 + b) * 16], (unsigned)(t + 2));
  }
}

}  // namespace

extern "C" void kernel_launch(void* const* d_in, const int* in_sizes, int n_in,
                              void* d_out, int out_size, void* d_ws, size_t ws_size,
                              hipStream_t stream) {
  const float* x  = (const float*)d_in[0];
  const float* Wh = (const float*)d_in[1];
  const float* Wx = (const float*)d_in[2];
  const float* bh = (const float*)d_in[3];
  const float* Ww = (const float*)d_in[4];

  float* out = (float*)d_out;
  float* hall = out;                                  // [B,T,D]
  float* out_tape = out + (size_t)kB * kT * kD;       // [B,N,D]
  float* out_h = out_tape + (size_t)kB * kN * kD;     // [B,D]

  // ws: [0,4096) hmark tags (64 x 64B lines); [4096,+192K) hsplit[2]; rw[2].
  unsigned* hmark = (unsigned*)d_ws;
  unsigned short* hsplit = (unsigned short*)((char*)d_ws + 4096);
  float* rw = (float*)((char*)d_ws + 4096 + 2 * kHS * (int)sizeof(unsigned short));

  hipMemsetAsync(d_ws, 0, 4096, stream);                             // tags = 0
  hipMemsetAsync((void*)rw, 0xFF, 2 * kRW * sizeof(float), stream);  // poison

  xproj_kernel<<<dim3(kD / 128, (kB * kT) / 128), 256, 0, stream>>>(x, Wx, hall);

  scan_kernel<<<64, 256, 0, stream>>>(Wh, Ww, bh, hall, hsplit, rw, hmark,
                                      out_tape, out_h);
}